// Round 1
// 1428.382 us; speedup vs baseline: 1.1348x; 1.1348x over previous
//
#include <hip/hip_runtime.h>

// Problem constants (fixed by setup_inputs)
#define HQ 32
#define HKV 32
#define DH 128
#define HID 4096
#define BATCH 4
#define SEQ 1024
#define TOK (BATCH * SEQ)          // 4096
#define NQKV 12288                 // (HQ + 2*HKV) * DH
#define CACHE_ROWS 8192            // NUM_BLOCKS * BLOCK_SIZE
#define SM_SCALE 0.08838834764831845f  // 1/sqrt(128)

typedef unsigned short u16;
typedef __bf16 bf16x8 __attribute__((ext_vector_type(8)));
typedef float floatx4 __attribute__((ext_vector_type(4)));

__device__ __forceinline__ u16 f2bf(float x) {
  unsigned u = __float_as_uint(x);
  u += 0x7FFF + ((u >> 16) & 1);   // RNE
  return (u16)(u >> 16);
}
__device__ __forceinline__ float bf2f(u16 h) {
  return __uint_as_float(((unsigned)h) << 16);
}
// async global->LDS, 16B per lane. LDS dest is wave-uniform base + lane*16:
// callers must pass per-lane pointers that are lane-contiguous within a wave.
__device__ __forceinline__ void cp16(const void* g, void* l) {
  __builtin_amdgcn_global_load_lds(
      (__attribute__((address_space(1))) unsigned int*)(g),
      (__attribute__((address_space(3))) unsigned int*)(l), 16, 0, 0);
}

// ---------------- fp32 -> bf16 elementwise ----------------
__global__ void k_f32_to_bf16(const float4* __restrict__ x, ushort4* __restrict__ y) {
  int i = blockIdx.x * 256 + threadIdx.x;
  float4 v = x[i];
  ushort4 o;
  o.x = f2bf(v.x); o.y = f2bf(v.y); o.z = f2bf(v.z); o.w = f2bf(v.w);
  y[i] = o;
}

// ---------------- fp32 KxN -> bf16 NxK transpose ----------------
__global__ void k_transpose_bf16(const float* __restrict__ W, u16* __restrict__ Wt,
                                 int Kd, int Nd) {
  __shared__ float t[64][65];
  int n0 = blockIdx.x << 6, k0 = blockIdx.y << 6;
  int tx = threadIdx.x & 63, ty = threadIdx.x >> 6;
#pragma unroll
  for (int r = ty; r < 64; r += 4)
    t[r][tx] = W[(size_t)(k0 + r) * Nd + n0 + tx];
  __syncthreads();
#pragma unroll
  for (int r = ty; r < 64; r += 4)
    Wt[(size_t)(n0 + r) * Kd + k0 + tx] = f2bf(t[tx][r]);
}

// ================= 256x256 8-phase bf16 GEMM =================
// C[M,N] = A[M,K] * Bt[N,K]^T, M = TOK = 4096 for both instantiations.
// 512 thr = 8 waves (2M x 4N); per-wave C = 128x64; BK=64.
// LDS: 2 dbuf x (A 256x64 + B 256x64) bf16 = 128 KiB -> 1 block/CU.
// Swizzle: phys 16B-slot = logical_slot ^ (row&7); DMA dest linear,
// global source pre-swizzled, ds_read applies same XOR (involution).
// Schedule per group g (computes K-tile t, c=t&1, o=c^1), 4 phases:
//   ph0: ds_read B-frags(all)+A-frags(mi 0,1); stage A0(t+1)->buf[o]
//   ph1: A-frags(mi 2,3);                      stage A1(t+1)->buf[o]
//   ph2: A-frags(mi 4,5);                      stage B0(t+2)->buf[c]
//   ph3: A-frags(mi 6,7);                      stage B1(t+2)->buf[c]
//   each phase: ... s_barrier; setprio(1); 16 MFMA; setprio(0);
//               [ph3 only: s_waitcnt vmcnt(4)]; s_barrier
// Safety: every staged region's last ds_read completed >=1 barrier before
// the stage is issued (B of tile t read only at ph0; A of t-1 read in the
// previous group). vmcnt(4) at ph3 guarantees tile t+1 fully in LDS
// (last 4 outstanding loads are the 2 B(t+2) halves). No drain-to-0 in loop.
template <int Nd, int Kd, bool OUT_BF16>
__global__ __launch_bounds__(512, 2) void k_gemm256(const u16* __restrict__ A,
                                                    const u16* __restrict__ Bt,
                                                    void* __restrict__ Cp) {
  constexpr int GX = Nd / 256;
  constexpr int NWG = (TOK / 256) * GX;
  __shared__ __align__(16) u16 lds[2][2][256 * 64];  // [buf][0=A,1=B]

  // XCD-chunked swizzle: hw bid%8 = XCD; give each XCD a contiguous chunk.
  const int bid = blockIdx.x;
  const int orig = (bid & 7) * (NWG / 8) + (bid >> 3);
  const int bx = orig % GX, by = orig / GX;
  const int bm = by << 8, bn = bx << 8;

  const int tid = threadIdx.x;
  const int wave = tid >> 6, lane = tid & 63;
  const int wm = wave >> 2, wn = wave & 3;
  const int quad = lane >> 4, l16 = lane & 15;

  // ---- staging: one 128x64 half-tile = 1024 granules of 16B, 2/thread ----
  // thread handles phys granules g=tid and g=tid+512 (lane-contiguous dest);
  // source column = (phys_slot ^ (row&7))*8 so linear DMA lands swizzled.
  auto stage_half = [&](const u16* src, int grow, int k0, u16* ldsb, int h) {
#pragma unroll
    for (int p = 0; p < 2; ++p) {
      int g = tid + (p << 9);
      int row = g >> 3, ps = g & 7;
      int ls = ps ^ (row & 7);
      cp16(src + (size_t)(grow + h * 128 + row) * Kd + k0 + ls * 8,
           ldsb + ((h * 128 + row) << 6) + (ps << 3));
    }
  };
  // swizzled ds_read address for logical (row, 8-elem slot)
  auto frag = [&](const u16* ldsb, int row, int slot) {
    return (const bf16x8*)(ldsb + (row << 6) + ((slot ^ (row & 7)) << 3));
  };

  const floatx4 FZ4 = {0.f, 0.f, 0.f, 0.f};
  floatx4 acc[8][4];
#pragma unroll
  for (int i = 0; i < 8; ++i)
#pragma unroll
    for (int j = 0; j < 4; ++j) acc[i][j] = FZ4;

  // ---- prologue: tile0 A+B -> buf0, tile1 B -> buf1 (12 loads/thread) ----
  stage_half(A, bm, 0, &lds[0][0][0], 0);
  stage_half(A, bm, 0, &lds[0][0][0], 1);
  stage_half(Bt, bn, 0, &lds[0][1][0], 0);
  stage_half(Bt, bn, 0, &lds[0][1][0], 1);
  stage_half(Bt, bn, 64, &lds[1][1][0], 0);
  stage_half(Bt, bn, 64, &lds[1][1][0], 1);
  asm volatile("s_waitcnt vmcnt(4)" ::: "memory");  // tile0 complete
  asm volatile("s_barrier" ::: "memory");

  constexpr int NT = Kd / 64;
  for (int t = 0; t < NT; ++t) {
    const int c = t & 1, o = c ^ 1;
    const u16* cA = &lds[c][0][0];
    const u16* cB = &lds[c][1][0];
    // tail: clamp prefetch k to the last tile (re-stages valid data, unused)
    const int k1 = (t + 1 < NT) ? (t + 1) * 64 : (Kd - 64);
    const int k2 = (t + 2 < NT) ? (t + 2) * 64 : (Kd - 64);

    bf16x8 bfr[4][2];  // B-frags held in regs for the whole group (32 VGPR)
#pragma unroll
    for (int ph = 0; ph < 4; ++ph) {
      if (ph == 0) {
#pragma unroll
        for (int ni = 0; ni < 4; ++ni)
#pragma unroll
          for (int ks = 0; ks < 2; ++ks)
            bfr[ni][ks] = *frag(cB, wn * 64 + ni * 16 + l16, ks * 4 + quad);
      }
      bf16x8 af[2][2];
#pragma unroll
      for (int m = 0; m < 2; ++m)
#pragma unroll
        for (int ks = 0; ks < 2; ++ks)
          af[m][ks] = *frag(cA, wm * 128 + (ph * 2 + m) * 16 + l16, ks * 4 + quad);

      if (ph == 0) stage_half(A, bm, k1, &lds[o][0][0], 0);
      else if (ph == 1) stage_half(A, bm, k1, &lds[o][0][0], 1);
      else if (ph == 2) stage_half(Bt, bn, k2, &lds[c][1][0], 0);
      else stage_half(Bt, bn, k2, &lds[c][1][0], 1);

      asm volatile("s_barrier" ::: "memory");
      __builtin_amdgcn_s_setprio(1);
#pragma unroll
      for (int m = 0; m < 2; ++m)
#pragma unroll
        for (int ni = 0; ni < 4; ++ni)
#pragma unroll
          for (int ks = 0; ks < 2; ++ks)
            acc[ph * 2 + m][ni] = __builtin_amdgcn_mfma_f32_16x16x32_bf16(
                af[m][ks], bfr[ni][ks], acc[ph * 2 + m][ni], 0, 0, 0);
      __builtin_amdgcn_s_setprio(0);
      if (ph == 3) asm volatile("s_waitcnt vmcnt(4)" ::: "memory");
      asm volatile("s_barrier" ::: "memory");
    }
  }
  // drain stray DMA before LDS is handed to the next block on this CU
  asm volatile("s_waitcnt vmcnt(0)" ::: "memory");

  // epilogue: C row = quad*4+r (+16*mi), col = l16 (+16*ni)
  const int rbase = bm + wm * 128 + quad * 4;
  const int cbase = bn + wn * 64 + l16;
#pragma unroll
  for (int mi = 0; mi < 8; ++mi)
#pragma unroll
    for (int ni = 0; ni < 4; ++ni)
#pragma unroll
      for (int r = 0; r < 4; ++r) {
        size_t idx = (size_t)(rbase + mi * 16 + r) * Nd + (cbase + ni * 16);
        if (OUT_BF16)
          ((u16*)Cp)[idx] = f2bf(acc[mi][ni][r]);
        else
          ((float*)Cp)[idx] = acc[mi][ni][r];
      }
}

// ---------------- RoPE + layout + cache scatter ----------------
__global__ void k_rope_scatter(const u16* __restrict__ qkv, const float* __restrict__ cosp,
                               const float* __restrict__ sinp, const int* __restrict__ slots,
                               u16* __restrict__ qb, u16* __restrict__ kb,
                               float* __restrict__ kc, float* __restrict__ vc) {
  const int t = blockIdx.x;
  const int b = t >> 10, s = t & 1023;
  const int tid = threadIdx.x;
  __shared__ float lc[64], ls[64];
  if (tid < 64) lc[tid] = cosp[t * 64 + tid];
  else if (tid < 128) ls[tid - 64] = sinp[t * 64 + (tid - 64)];
  __syncthreads();
  const int slot = slots[t];
  const u16* base = qkv + (size_t)t * NQKV;
#pragma unroll
  for (int it = 0; it < 8; ++it) {  // Q: 32 heads x 64 pairs
    int w = it * 256 + tid;
    int h = w >> 6, i = w & 63;
    float x1 = bf2f(base[h * 128 + i]);
    float x2 = bf2f(base[h * 128 + 64 + i]);
    float c = lc[i], sn = ls[i];
    size_t o = ((size_t)(b * HQ + h) * SEQ + s) * DH + i;
    qb[o] = f2bf((x1 * c - x2 * sn) * SM_SCALE);
    qb[o + 64] = f2bf((x2 * c + x1 * sn) * SM_SCALE);
  }
#pragma unroll
  for (int it = 0; it < 8; ++it) {  // K
    int w = it * 256 + tid;
    int h = w >> 6, i = w & 63;
    float x1 = bf2f(base[HQ * DH + h * 128 + i]);
    float x2 = bf2f(base[HQ * DH + h * 128 + 64 + i]);
    float c = lc[i], sn = ls[i];
    float y1 = x1 * c - x2 * sn;
    float y2 = x2 * c + x1 * sn;
    size_t o = ((size_t)(b * HKV + h) * SEQ + s) * DH + i;
    kb[o] = f2bf(y1);
    kb[o + 64] = f2bf(y2);
    size_t oc = (size_t)slot * (HKV * DH) + h * 128 + i;
    kc[oc] = y1;
    kc[oc + 64] = y2;
  }
#pragma unroll
  for (int it = 0; it < 16; ++it) {  // V -> cache (no rope)
    int w = it * 256 + tid;
    vc[(size_t)slot * (HKV * DH) + w] = bf2f(base[2 * HQ * DH + w]);
  }
}

// ---------------- V transpose: qkv v-slice -> vT (b,h,d,s) bf16 ----------------
__global__ void k_vt(const u16* __restrict__ qkv, u16* __restrict__ vT) {
  __shared__ u16 t[64][66];
  const int bh = blockIdx.z;
  const int b = bh >> 5, h = bh & 31;
  const int s0 = blockIdx.y << 6, d0 = blockIdx.x << 6;
  const int tx = threadIdx.x & 63, ty = threadIdx.x >> 6;
#pragma unroll
  for (int r = ty; r < 64; r += 4)
    t[r][tx] = qkv[(size_t)(b * SEQ + s0 + r) * NQKV + 2 * HQ * DH + h * DH + d0 + tx];
  __syncthreads();
#pragma unroll
  for (int r = ty; r < 64; r += 4)
    vT[((size_t)bh * DH + d0 + r) * SEQ + s0 + tx] = t[tx][r];
}

// ---------------- flash attention (causal) ----------------
__global__ __launch_bounds__(256, 2) void k_attn(const u16* __restrict__ qb,
                                                 const u16* __restrict__ kb,
                                                 const u16* __restrict__ vT,
                                                 u16* __restrict__ attn) {
  __shared__ __align__(16) u16 lK[64 * 128];  // [ki][d]
  __shared__ __align__(16) u16 lV[128 * 64];  // [d][ki]
  __shared__ __align__(16) u16 lP[64 * 64];   // [q][ki]
  const int qt = blockIdx.x, h = blockIdx.y, b = blockIdx.z;
  const int bh = b * HQ + h;
  const int q0 = qt << 6;
  const int tid = threadIdx.x, wave = tid >> 6, lane = tid & 63;
  const int quad = lane >> 4, l16 = lane & 15;
  const u16* Qb = qb + (size_t)bh * SEQ * DH;
  const u16* Kb = kb + (size_t)bh * SEQ * DH;
  const u16* Vb = vT + (size_t)bh * DH * SEQ;

  bf16x8 qf[4];
#pragma unroll
  for (int ds = 0; ds < 4; ++ds)
    qf[ds] = *(const bf16x8*)&Qb[(size_t)(q0 + wave * 16 + l16) * DH + ds * 32 + quad * 8];

  const floatx4 FZ4 = {0.f, 0.f, 0.f, 0.f};
  floatx4 acc_o[8];
#pragma unroll
  for (int i = 0; i < 8; ++i) acc_o[i] = FZ4;
  float m_i[4] = {-1e30f, -1e30f, -1e30f, -1e30f};
  float l_i[4] = {0.f, 0.f, 0.f, 0.f};

  for (int kt = 0; kt <= qt; ++kt) {
    const int k0 = kt << 6;
    __syncthreads();
    const u16* Ks = Kb + (size_t)k0 * DH;
#pragma unroll
    for (int p = 0; p < 4; ++p) {
      int c = tid + p * 256;
      cp16(Ks + c * 8, &lK[c * 8]);
    }
#pragma unroll
    for (int p = 0; p < 4; ++p) {
      int c = tid + p * 256;
      cp16(Vb + (size_t)(c >> 3) * SEQ + k0 + (c & 7) * 8, &lV[c * 8]);
    }
    __syncthreads();

    floatx4 accs[4];
#pragma unroll
    for (int ni = 0; ni < 4; ++ni) {
      accs[ni] = FZ4;
#pragma unroll
      for (int ds = 0; ds < 4; ++ds) {
        bf16x8 kf = *(const bf16x8*)&lK[(ni * 16 + l16) * 128 + ds * 32 + quad * 8];
        accs[ni] = __builtin_amdgcn_mfma_f32_16x16x32_bf16(qf[ds], kf, accs[ni], 0, 0, 0);
      }
    }
    if (kt == qt) {
#pragma unroll
      for (int ni = 0; ni < 4; ++ni) {
        int ki = k0 + ni * 16 + l16;
#pragma unroll
        for (int r = 0; r < 4; ++r) {
          int qr = q0 + wave * 16 + quad * 4 + r;
          if (ki > qr) accs[ni][r] = -1e30f;
        }
      }
    }
    float mnew[4], alpha[4];
#pragma unroll
    for (int r = 0; r < 4; ++r) {
      float mx = fmaxf(fmaxf(accs[0][r], accs[1][r]), fmaxf(accs[2][r], accs[3][r]));
#pragma unroll
      for (int off = 1; off < 16; off <<= 1) mx = fmaxf(mx, __shfl_xor(mx, off));
      mnew[r] = fmaxf(m_i[r], mx);
      alpha[r] = __expf(m_i[r] - mnew[r]);
      m_i[r] = mnew[r];
    }
    float rs[4] = {0.f, 0.f, 0.f, 0.f};
#pragma unroll
    for (int ni = 0; ni < 4; ++ni)
#pragma unroll
      for (int r = 0; r < 4; ++r) {
        float p = __expf(accs[ni][r] - mnew[r]);
        rs[r] += p;
        lP[(wave * 16 + quad * 4 + r) * 64 + ni * 16 + l16] = f2bf(p);
      }
#pragma unroll
    for (int r = 0; r < 4; ++r) {
      float sr = rs[r];
#pragma unroll
      for (int off = 1; off < 16; off <<= 1) sr += __shfl_xor(sr, off);
      l_i[r] = l_i[r] * alpha[r] + sr;
    }
#pragma unroll
    for (int dt = 0; dt < 8; ++dt)
#pragma unroll
      for (int r = 0; r < 4; ++r) acc_o[dt][r] *= alpha[r];

    bf16x8 pf[2];
#pragma unroll
    for (int ks = 0; ks < 2; ++ks)
      pf[ks] = *(const bf16x8*)&lP[(wave * 16 + l16) * 64 + ks * 32 + quad * 8];
#pragma unroll
    for (int dt = 0; dt < 8; ++dt)
#pragma unroll
      for (int ks = 0; ks < 2; ++ks) {
        bf16x8 vf = *(const bf16x8*)&lV[(dt * 16 + l16) * 64 + ks * 32 + quad * 8];
        acc_o[dt] = __builtin_amdgcn_mfma_f32_16x16x32_bf16(pf[ks], vf, acc_o[dt], 0, 0, 0);
      }
  }
  float inv[4];
#pragma unroll
  for (int r = 0; r < 4; ++r) inv[r] = 1.0f / l_i[r];
#pragma unroll
  for (int dt = 0; dt < 8; ++dt)
#pragma unroll
    for (int r = 0; r < 4; ++r) {
      int tok = b * SEQ + q0 + wave * 16 + quad * 4 + r;
      attn[(size_t)tok * HID + h * DH + dt * 16 + l16] = f2bf(acc_o[dt][r] * inv[r]);
    }
}

// ---------------- launcher ----------------
extern "C" void kernel_launch(void* const* d_in, const int* in_sizes, int n_in,
                              void* d_out, int out_size, void* d_ws, size_t ws_size,
                              hipStream_t stream) {
  (void)in_sizes; (void)n_in; (void)out_size; (void)ws_size;
  const float* hs = (const float*)d_in[0];
  const float* cosp = (const float*)d_in[1];
  const float* sinp = (const float*)d_in[2];
  const float* qkv_w = (const float*)d_in[3];
  const float* o_w = (const float*)d_in[4];
  const int* slots = (const int*)d_in[8];

  float* out = (float*)d_out;                          // (T, HID) fp32
  float* kc = out + (size_t)TOK * HID;                 // (8192, 32, 128) fp32
  float* vc = kc + (size_t)CACHE_ROWS * HKV * DH;

  // workspace layout (224 MiB), stream-ordered aliasing:
  //  regA (96MB): W1t  -> then qb | kb | vT
  //  regB (96MB): qkv  -> then W2t (after v-transpose consumed qkv)
  //  regC (32MB): hs_bf16 -> then attn
  u16* regA = (u16*)d_ws;
  u16* regB = regA + (size_t)NQKV * HID;
  u16* regC = regB + (size_t)TOK * NQKV;
  u16* W1t = regA;
  u16* qb = regA;
  u16* kb = qb + (size_t)BATCH * HQ * SEQ * DH;
  u16* vTp = kb + (size_t)BATCH * HKV * SEQ * DH;
  u16* qkv = regB;
  u16* W2t = regB;
  u16* hsb = regC;
  u16* attnb = regC;

  hipMemsetAsync(kc, 0, (size_t)2 * CACHE_ROWS * HKV * DH * sizeof(float), stream);

  k_f32_to_bf16<<<TOK * HID / 1024, 256, 0, stream>>>((const float4*)hs, (ushort4*)hsb);
  k_transpose_bf16<<<dim3(NQKV / 64, HID / 64), 256, 0, stream>>>(qkv_w, W1t, HID, NQKV);
  k_gemm256<NQKV, HID, true>
      <<<(TOK / 256) * (NQKV / 256), 512, 0, stream>>>(hsb, W1t, qkv);
  k_rope_scatter<<<TOK, 256, 0, stream>>>(qkv, cosp, sinp, slots, qb, kb, kc, vc);
  k_vt<<<dim3(DH / 64, SEQ / 64, BATCH * HKV), 256, 0, stream>>>(qkv, vTp);
  k_transpose_bf16<<<dim3(HID / 64, HID / 64), 256, 0, stream>>>(o_w, W2t, HID, HID);
  k_attn<<<dim3(SEQ / 64, HQ, BATCH), 256, 0, stream>>>(qb, kb, vTp, attnb);
  k_gemm256<HID, HID, false>
      <<<(TOK / 256) * (HID / 256), 512, 0, stream>>>(attnb, W2t, out);
}

// Round 2
// 1320.709 us; speedup vs baseline: 1.2273x; 1.0815x over previous
//
#include <hip/hip_runtime.h>

// Problem constants (fixed by setup_inputs)
#define HQ 32
#define HKV 32
#define DH 128
#define HID 4096
#define BATCH 4
#define SEQ 1024
#define TOK (BATCH * SEQ)          // 4096
#define NQKV 12288                 // (HQ + 2*HKV) * DH
#define CACHE_ROWS 8192            // NUM_BLOCKS * BLOCK_SIZE
#define SM_SCALE 0.08838834764831845f  // 1/sqrt(128)

typedef unsigned short u16;
typedef __bf16 bf16x8 __attribute__((ext_vector_type(8)));
typedef float floatx4 __attribute__((ext_vector_type(4)));
typedef u16 u16x8 __attribute__((ext_vector_type(8)));
typedef u16 u16x4 __attribute__((ext_vector_type(4)));

__device__ __forceinline__ u16 f2bf(float x) {
  unsigned u = __float_as_uint(x);
  u += 0x7FFF + ((u >> 16) & 1);   // RNE
  return (u16)(u >> 16);
}
__device__ __forceinline__ float bf2f(u16 h) {
  return __uint_as_float(((unsigned)h) << 16);
}
// async global->LDS, 16B per lane. LDS dest is wave-uniform base + lane*16:
// callers must pass per-lane pointers that are lane-contiguous within a wave.
__device__ __forceinline__ void cp16(const void* g, void* l) {
  __builtin_amdgcn_global_load_lds(
      (__attribute__((address_space(1))) unsigned int*)(g),
      (__attribute__((address_space(3))) unsigned int*)(l), 16, 0, 0);
}

// ---------------- fp32 -> bf16 elementwise ----------------
__global__ void k_f32_to_bf16(const float4* __restrict__ x, ushort4* __restrict__ y) {
  int i = blockIdx.x * 256 + threadIdx.x;
  float4 v = x[i];
  ushort4 o;
  o.x = f2bf(v.x); o.y = f2bf(v.y); o.z = f2bf(v.z); o.w = f2bf(v.w);
  y[i] = o;
}

// ---------------- fp32 KxN -> bf16 NxK transpose ----------------
// read coalesced fp32; write ushort4 (4 k per lane) for 512B/wave-instr stores
__global__ void k_transpose_bf16(const float* __restrict__ W, u16* __restrict__ Wt,
                                 int Kd, int Nd) {
  __shared__ float t[64][65];
  int n0 = blockIdx.x << 6, k0 = blockIdx.y << 6;
  int tx = threadIdx.x & 63, ty = threadIdx.x >> 6;
#pragma unroll
  for (int r = ty; r < 64; r += 4)
    t[r][tx] = W[(size_t)(k0 + r) * Nd + n0 + tx];
  __syncthreads();
  const int kg = threadIdx.x & 15, nr = threadIdx.x >> 4;  // kg: k-group, nr: 0..15
#pragma unroll
  for (int q = 0; q < 4; ++q) {
    int n = q * 16 + nr;
    u16x4 o;
#pragma unroll
    for (int j = 0; j < 4; ++j) o[j] = f2bf(t[kg * 4 + j][n]);
    *(u16x4*)&Wt[(size_t)(n0 + n) * Kd + k0 + kg * 4] = o;
  }
}

// ================= 256x256 8-phase bf16 GEMM (unchanged, proven) =================
template <int Nd, int Kd, bool OUT_BF16>
__global__ __launch_bounds__(512, 2) void k_gemm256(const u16* __restrict__ A,
                                                    const u16* __restrict__ Bt,
                                                    void* __restrict__ Cp) {
  constexpr int GX = Nd / 256;
  constexpr int NWG = (TOK / 256) * GX;
  __shared__ __align__(16) u16 lds[2][2][256 * 64];  // [buf][0=A,1=B]

  const int bid = blockIdx.x;
  const int orig = (bid & 7) * (NWG / 8) + (bid >> 3);
  const int bx = orig % GX, by = orig / GX;
  const int bm = by << 8, bn = bx << 8;

  const int tid = threadIdx.x;
  const int wave = tid >> 6, lane = tid & 63;
  const int wm = wave >> 2, wn = wave & 3;
  const int quad = lane >> 4, l16 = lane & 15;

  auto stage_half = [&](const u16* src, int grow, int k0, u16* ldsb, int h) {
#pragma unroll
    for (int p = 0; p < 2; ++p) {
      int g = tid + (p << 9);
      int row = g >> 3, ps = g & 7;
      int ls = ps ^ (row & 7);
      cp16(src + (size_t)(grow + h * 128 + row) * Kd + k0 + ls * 8,
           ldsb + ((h * 128 + row) << 6) + (ps << 3));
    }
  };
  auto frag = [&](const u16* ldsb, int row, int slot) {
    return (const bf16x8*)(ldsb + (row << 6) + ((slot ^ (row & 7)) << 3));
  };

  const floatx4 FZ4 = {0.f, 0.f, 0.f, 0.f};
  floatx4 acc[8][4];
#pragma unroll
  for (int i = 0; i < 8; ++i)
#pragma unroll
    for (int j = 0; j < 4; ++j) acc[i][j] = FZ4;

  stage_half(A, bm, 0, &lds[0][0][0], 0);
  stage_half(A, bm, 0, &lds[0][0][0], 1);
  stage_half(Bt, bn, 0, &lds[0][1][0], 0);
  stage_half(Bt, bn, 0, &lds[0][1][0], 1);
  stage_half(Bt, bn, 64, &lds[1][1][0], 0);
  stage_half(Bt, bn, 64, &lds[1][1][0], 1);
  asm volatile("s_waitcnt vmcnt(4)" ::: "memory");
  asm volatile("s_barrier" ::: "memory");

  constexpr int NT = Kd / 64;
  for (int t = 0; t < NT; ++t) {
    const int c = t & 1, o = c ^ 1;
    const u16* cA = &lds[c][0][0];
    const u16* cB = &lds[c][1][0];
    const int k1 = (t + 1 < NT) ? (t + 1) * 64 : (Kd - 64);
    const int k2 = (t + 2 < NT) ? (t + 2) * 64 : (Kd - 64);

    bf16x8 bfr[4][2];
#pragma unroll
    for (int ph = 0; ph < 4; ++ph) {
      if (ph == 0) {
#pragma unroll
        for (int ni = 0; ni < 4; ++ni)
#pragma unroll
          for (int ks = 0; ks < 2; ++ks)
            bfr[ni][ks] = *frag(cB, wn * 64 + ni * 16 + l16, ks * 4 + quad);
      }
      bf16x8 af[2][2];
#pragma unroll
      for (int m = 0; m < 2; ++m)
#pragma unroll
        for (int ks = 0; ks < 2; ++ks)
          af[m][ks] = *frag(cA, wm * 128 + (ph * 2 + m) * 16 + l16, ks * 4 + quad);

      if (ph == 0) stage_half(A, bm, k1, &lds[o][0][0], 0);
      else if (ph == 1) stage_half(A, bm, k1, &lds[o][0][0], 1);
      else if (ph == 2) stage_half(Bt, bn, k2, &lds[c][1][0], 0);
      else stage_half(Bt, bn, k2, &lds[c][1][0], 1);

      asm volatile("s_barrier" ::: "memory");
      __builtin_amdgcn_s_setprio(1);
#pragma unroll
      for (int m = 0; m < 2; ++m)
#pragma unroll
        for (int ni = 0; ni < 4; ++ni)
#pragma unroll
          for (int ks = 0; ks < 2; ++ks)
            acc[ph * 2 + m][ni] = __builtin_amdgcn_mfma_f32_16x16x32_bf16(
                af[m][ks], bfr[ni][ks], acc[ph * 2 + m][ni], 0, 0, 0);
      __builtin_amdgcn_s_setprio(0);
      if (ph == 3) asm volatile("s_waitcnt vmcnt(4)" ::: "memory");
      asm volatile("s_barrier" ::: "memory");
    }
  }
  asm volatile("s_waitcnt vmcnt(0)" ::: "memory");

  const int rbase = bm + wm * 128 + quad * 4;
  const int cbase = bn + wn * 64 + l16;
#pragma unroll
  for (int mi = 0; mi < 8; ++mi)
#pragma unroll
    for (int ni = 0; ni < 4; ++ni)
#pragma unroll
      for (int r = 0; r < 4; ++r) {
        size_t idx = (size_t)(rbase + mi * 16 + r) * Nd + (cbase + ni * 16);
        if (OUT_BF16)
          ((u16*)Cp)[idx] = f2bf(acc[mi][ni][r]);
        else
          ((float*)Cp)[idx] = acc[mi][ni][r];
      }
}

// ---------------- RoPE + layout + cache scatter (vectorized) ----------------
// 256 thr/token: thread = (head h = tid>>3, 8-elem group i0 = (tid&7)*8)
__global__ void k_rope_scatter(const u16* __restrict__ qkv, const float* __restrict__ cosp,
                               const float* __restrict__ sinp, const int* __restrict__ slots,
                               u16* __restrict__ qb, u16* __restrict__ kb,
                               float* __restrict__ kc, float* __restrict__ vc) {
  const int t = blockIdx.x;
  const int b = t >> 10, s = t & 1023;
  const int tid = threadIdx.x;
  __shared__ float lc[64], ls[64];
  if (tid < 64) lc[tid] = cosp[t * 64 + tid];
  else if (tid < 128) ls[tid - 64] = sinp[t * 64 + (tid - 64)];
  __syncthreads();
  const int slot = slots[t];
  const u16* base = qkv + (size_t)t * NQKV;
  const int h = tid >> 3, i0 = (tid & 7) << 3;
  float c[8], sn[8];
#pragma unroll
  for (int j = 0; j < 8; ++j) { c[j] = lc[i0 + j]; sn[j] = ls[i0 + j]; }

  {  // Q (scale folded)
    u16x8 x1 = *(const u16x8*)&base[h * 128 + i0];
    u16x8 x2 = *(const u16x8*)&base[h * 128 + 64 + i0];
    u16x8 y1, y2;
#pragma unroll
    for (int j = 0; j < 8; ++j) {
      float a = bf2f(x1[j]), d = bf2f(x2[j]);
      y1[j] = f2bf((a * c[j] - d * sn[j]) * SM_SCALE);
      y2[j] = f2bf((d * c[j] + a * sn[j]) * SM_SCALE);
    }
    size_t o = ((size_t)(b * HQ + h) * SEQ + s) * DH + i0;
    *(u16x8*)&qb[o] = y1;
    *(u16x8*)&qb[o + 64] = y2;
  }
  {  // K: bf16 kb + fp32 cache
    u16x8 x1 = *(const u16x8*)&base[HQ * DH + h * 128 + i0];
    u16x8 x2 = *(const u16x8*)&base[HQ * DH + h * 128 + 64 + i0];
    u16x8 y1, y2;
    float f1[8], f2[8];
#pragma unroll
    for (int j = 0; j < 8; ++j) {
      float a = bf2f(x1[j]), d = bf2f(x2[j]);
      f1[j] = a * c[j] - d * sn[j];
      f2[j] = d * c[j] + a * sn[j];
      y1[j] = f2bf(f1[j]);
      y2[j] = f2bf(f2[j]);
    }
    size_t o = ((size_t)(b * HKV + h) * SEQ + s) * DH + i0;
    *(u16x8*)&kb[o] = y1;
    *(u16x8*)&kb[o + 64] = y2;
    size_t oc = (size_t)slot * (HKV * DH) + h * 128 + i0;
    *(float4*)&kc[oc]      = make_float4(f1[0], f1[1], f1[2], f1[3]);
    *(float4*)&kc[oc + 4]  = make_float4(f1[4], f1[5], f1[6], f1[7]);
    *(float4*)&kc[oc + 64] = make_float4(f2[0], f2[1], f2[2], f2[3]);
    *(float4*)&kc[oc + 68] = make_float4(f2[4], f2[5], f2[6], f2[7]);
  }
  {  // V -> fp32 cache; thread owns 16 consecutive channels
    const int vo = tid * 16;
    u16x8 va = *(const u16x8*)&base[2 * HQ * DH + vo];
    u16x8 vb2 = *(const u16x8*)&base[2 * HQ * DH + vo + 8];
    float* vd = vc + (size_t)slot * (HKV * DH) + vo;
    *(float4*)&vd[0]  = make_float4(bf2f(va[0]), bf2f(va[1]), bf2f(va[2]), bf2f(va[3]));
    *(float4*)&vd[4]  = make_float4(bf2f(va[4]), bf2f(va[5]), bf2f(va[6]), bf2f(va[7]));
    *(float4*)&vd[8]  = make_float4(bf2f(vb2[0]), bf2f(vb2[1]), bf2f(vb2[2]), bf2f(vb2[3]));
    *(float4*)&vd[12] = make_float4(bf2f(vb2[4]), bf2f(vb2[5]), bf2f(vb2[6]), bf2f(vb2[7]));
  }
}

// ---------------- V transpose: qkv v-slice -> vT (b,h,d,s) bf16 ----------------
// vectorized: 8B loads, 8B stores
__global__ void k_vt(const u16* __restrict__ qkv, u16* __restrict__ vT) {
  __shared__ u16 t[64][66];
  const int bh = blockIdx.z;
  const int b = bh >> 5, h = bh & 31;
  const int s0 = blockIdx.y << 6, d0 = blockIdx.x << 6;
  const int cg = threadIdx.x & 15, rr = threadIdx.x >> 4;  // 16 col-groups x 16 rows
#pragma unroll
  for (int q = 0; q < 4; ++q) {
    int r = q * 16 + rr;
    u16x4 v = *(const u16x4*)&qkv[(size_t)(b * SEQ + s0 + r) * NQKV + 2 * HQ * DH +
                                  h * DH + d0 + cg * 4];
    *(u16x4*)&t[r][cg * 4] = v;
  }
  __syncthreads();
#pragma unroll
  for (int q = 0; q < 4; ++q) {
    int d = q * 16 + rr;
    u16x4 o;
#pragma unroll
    for (int j = 0; j < 4; ++j) o[j] = t[cg * 4 + j][d];
    *(u16x4*)&vT[((size_t)bh * DH + d0 + d) * SEQ + s0 + cg * 4] = o;
  }
}

// ---------------- flash attention (causal) ----------------
// dbuf K/V LDS + counted vmcnt pipeline; XOR-swizzled LDS (conflict-free reads).
// LDS element map: lK[row][col] at row*128 + ((col>>3)^(row&15))*8 + (col&7)
//                  lV/lP[row][col] at row*64 + ((col>>3)^(row&7))*8 + (col&7)
// Staging keeps LDS dest linear (cp16 rule) and pre-swizzles the GLOBAL source.
__global__ __launch_bounds__(256, 2) void k_attn(const u16* __restrict__ qb,
                                                 const u16* __restrict__ kb,
                                                 const u16* __restrict__ vT,
                                                 u16* __restrict__ attn) {
  __shared__ __align__(16) u16 lK[2][64 * 128];
  __shared__ __align__(16) u16 lV[2][128 * 64];
  __shared__ __align__(16) u16 lP[64 * 64];
  const int qt = blockIdx.x, h = blockIdx.y, b = blockIdx.z;
  const int bh = b * HQ + h;
  const int q0 = qt << 6;
  const int tid = threadIdx.x, wave = tid >> 6, lane = tid & 63;
  const int quad = lane >> 4, l16 = lane & 15;
  const u16* Qb = qb + (size_t)bh * SEQ * DH;
  const u16* Kb = kb + (size_t)bh * SEQ * DH;
  const u16* Vb = vT + (size_t)bh * DH * SEQ;

  bf16x8 qf[4];
#pragma unroll
  for (int ds = 0; ds < 4; ++ds)
    qf[ds] = *(const bf16x8*)&Qb[(size_t)(q0 + wave * 16 + l16) * DH + ds * 32 + quad * 8];

  const floatx4 FZ4 = {0.f, 0.f, 0.f, 0.f};
  floatx4 acc_o[8];
#pragma unroll
  for (int i = 0; i < 8; ++i) acc_o[i] = FZ4;
  float m_i[4] = {-1e30f, -1e30f, -1e30f, -1e30f};
  float l_i[4] = {0.f, 0.f, 0.f, 0.f};

  auto stageK = [&](int buf, int k0) {
#pragma unroll
    for (int p = 0; p < 4; ++p) {
      int g = tid + (p << 8);               // granule 0..1023 of [64][128]
      int row = g >> 4, gs = g & 15;
      int sl = gs ^ (row & 15);             // pre-swizzled source column
      cp16(Kb + (size_t)(k0 + row) * DH + sl * 8, &lK[buf][g * 8]);
    }
  };
  auto stageV = [&](int buf, int k0) {
#pragma unroll
    for (int p = 0; p < 4; ++p) {
      int g = tid + (p << 8);               // granule 0..1023 of [128][64]
      int row = g >> 3, gs = g & 7;         // row = d
      int sl = gs ^ (row & 7);
      cp16(Vb + (size_t)row * SEQ + k0 + sl * 8, &lV[buf][g * 8]);
    }
  };

  stageK(0, 0);
  stageV(0, 0);
  for (int kt = 0; kt <= qt; ++kt) {
    const int cur = kt & 1;
    const int k0 = kt << 6;
    if (kt < qt) {
      stageK(cur ^ 1, k0 + 64);
      stageV(cur ^ 1, k0 + 64);
      asm volatile("s_waitcnt vmcnt(8)" ::: "memory");  // cur's 8 done; 8 in flight
    } else {
      asm volatile("s_waitcnt vmcnt(0)" ::: "memory");
    }
    __builtin_amdgcn_s_barrier();  // tile cur visible to all waves

    // S = Q K^T (scale folded in Q); swizzled kf reads are conflict-free
    floatx4 accs[4];
    __builtin_amdgcn_s_setprio(1);
#pragma unroll
    for (int ni = 0; ni < 4; ++ni) {
      accs[ni] = FZ4;
      const int row = ni * 16 + l16;
#pragma unroll
      for (int ds = 0; ds < 4; ++ds) {
        bf16x8 kf = *(const bf16x8*)&lK[cur][row * 128 + (((ds * 4 + quad) ^ (row & 15)) << 3)];
        accs[ni] = __builtin_amdgcn_mfma_f32_16x16x32_bf16(qf[ds], kf, accs[ni], 0, 0, 0);
      }
    }
    __builtin_amdgcn_s_setprio(0);
    if (kt == qt) {  // diagonal tile: causal mask
#pragma unroll
      for (int ni = 0; ni < 4; ++ni) {
        int ki = k0 + ni * 16 + l16;
#pragma unroll
        for (int r = 0; r < 4; ++r) {
          int qr = q0 + wave * 16 + quad * 4 + r;
          if (ki > qr) accs[ni][r] = -1e30f;
        }
      }
    }
    // online softmax; rows live on 16 lanes of a quad
    float mnew[4], alpha[4];
#pragma unroll
    for (int r = 0; r < 4; ++r) {
      float mx = fmaxf(fmaxf(accs[0][r], accs[1][r]), fmaxf(accs[2][r], accs[3][r]));
#pragma unroll
      for (int off = 1; off < 16; off <<= 1) mx = fmaxf(mx, __shfl_xor(mx, off));
      mnew[r] = fmaxf(m_i[r], mx);
      alpha[r] = __expf(m_i[r] - mnew[r]);
      m_i[r] = mnew[r];
    }
    float rs[4] = {0.f, 0.f, 0.f, 0.f};
#pragma unroll
    for (int ni = 0; ni < 4; ++ni)
#pragma unroll
      for (int r = 0; r < 4; ++r) {
        float p = __expf(accs[ni][r] - mnew[r]);
        rs[r] += p;
        int prow = wave * 16 + quad * 4 + r, pcol = ni * 16 + l16;
        lP[prow * 64 + ((((pcol >> 3) ^ (prow & 7))) << 3) + (pcol & 7)] = f2bf(p);
      }
#pragma unroll
    for (int r = 0; r < 4; ++r) {
      float sr = rs[r];
#pragma unroll
      for (int off = 1; off < 16; off <<= 1) sr += __shfl_xor(sr, off);
      l_i[r] = l_i[r] * alpha[r] + sr;
    }
#pragma unroll
    for (int dt = 0; dt < 8; ++dt)
#pragma unroll
      for (int r = 0; r < 4; ++r) acc_o[dt][r] *= alpha[r];

    // O += P V (wave-local P rows; swizzled pf/vf reads)
    bf16x8 pf[2];
    const int prow = wave * 16 + l16;
#pragma unroll
    for (int ks = 0; ks < 2; ++ks)
      pf[ks] = *(const bf16x8*)&lP[prow * 64 + (((ks * 4 + quad) ^ (prow & 7)) << 3)];
    __builtin_amdgcn_s_setprio(1);
#pragma unroll
    for (int dt = 0; dt < 8; ++dt) {
      const int vrow = dt * 16 + l16;
#pragma unroll
      for (int ks = 0; ks < 2; ++ks) {
        bf16x8 vf = *(const bf16x8*)&lV[cur][vrow * 64 + (((ks * 4 + quad) ^ (vrow & 7)) << 3)];
        acc_o[dt] = __builtin_amdgcn_mfma_f32_16x16x32_bf16(pf[ks], vf, acc_o[dt], 0, 0, 0);
      }
    }
    __builtin_amdgcn_s_setprio(0);
    // all LDS reads of tile cur retired before next iter restages cur^1's buddy
    asm volatile("s_waitcnt lgkmcnt(0)" ::: "memory");
    __builtin_amdgcn_s_barrier();
  }
  float inv[4];
#pragma unroll
  for (int r = 0; r < 4; ++r) inv[r] = 1.0f / l_i[r];
#pragma unroll
  for (int dt = 0; dt < 8; ++dt)
#pragma unroll
    for (int r = 0; r < 4; ++r) {
      int tok = b * SEQ + q0 + wave * 16 + quad * 4 + r;
      attn[(size_t)tok * HID + h * DH + dt * 16 + l16] = f2bf(acc_o[dt][r] * inv[r]);
    }
}

// ---------------- launcher ----------------
extern "C" void kernel_launch(void* const* d_in, const int* in_sizes, int n_in,
                              void* d_out, int out_size, void* d_ws, size_t ws_size,
                              hipStream_t stream) {
  (void)in_sizes; (void)n_in; (void)out_size; (void)ws_size;
  const float* hs = (const float*)d_in[0];
  const float* cosp = (const float*)d_in[1];
  const float* sinp = (const float*)d_in[2];
  const float* qkv_w = (const float*)d_in[3];
  const float* o_w = (const float*)d_in[4];
  const int* slots = (const int*)d_in[8];

  float* out = (float*)d_out;                          // (T, HID) fp32
  float* kc = out + (size_t)TOK * HID;                 // (8192, 32, 128) fp32
  float* vc = kc + (size_t)CACHE_ROWS * HKV * DH;

  // workspace layout (224 MiB), stream-ordered aliasing:
  //  regA (96MB): W1t  -> then qb | kb | vT
  //  regB (96MB): qkv  -> then W2t (after v-transpose consumed qkv)
  //  regC (32MB): hs_bf16 -> then attn
  u16* regA = (u16*)d_ws;
  u16* regB = regA + (size_t)NQKV * HID;
  u16* regC = regB + (size_t)TOK * NQKV;
  u16* W1t = regA;
  u16* qb = regA;
  u16* kb = qb + (size_t)BATCH * HQ * SEQ * DH;
  u16* vTp = kb + (size_t)BATCH * HKV * SEQ * DH;
  u16* qkv = regB;
  u16* W2t = regB;
  u16* hsb = regC;
  u16* attnb = regC;

  // slots = arange(TOK) fully overwrites cache rows [0, TOK); zero only the rest
  const size_t halfRows = (size_t)(CACHE_ROWS - TOK) * HKV * DH;
  hipMemsetAsync(kc + (size_t)TOK * HKV * DH, 0, halfRows * sizeof(float), stream);
  hipMemsetAsync(vc + (size_t)TOK * HKV * DH, 0, halfRows * sizeof(float), stream);

  k_f32_to_bf16<<<TOK * HID / 1024, 256, 0, stream>>>((const float4*)hs, (ushort4*)hsb);
  k_transpose_bf16<<<dim3(NQKV / 64, HID / 64), 256, 0, stream>>>(qkv_w, W1t, HID, NQKV);
  k_gemm256<NQKV, HID, true>
      <<<(TOK / 256) * (NQKV / 256), 512, 0, stream>>>(hsb, W1t, qkv);
  k_rope_scatter<<<TOK, 256, 0, stream>>>(qkv, cosp, sinp, slots, qb, kb, kc, vc);
  k_vt<<<dim3(DH / 64, SEQ / 64, BATCH * HKV), 256, 0, stream>>>(qkv, vTp);
  k_transpose_bf16<<<dim3(HID / 64, HID / 64), 256, 0, stream>>>(o_w, W2t, HID, HID);
  k_attn<<<dim3(SEQ / 64, HQ, BATCH), 256, 0, stream>>>(qb, kb, vTp, attnb);
  k_gemm256<HID, HID, false>
      <<<(TOK / 256) * (HID / 256), 512, 0, stream>>>(attnb, W2t, out);
}

// Round 3
// 1277.983 us; speedup vs baseline: 1.2684x; 1.0334x over previous
//
#include <hip/hip_runtime.h>

// Problem constants (fixed by setup_inputs)
#define HQ 32
#define HKV 32
#define DH 128
#define HID 4096
#define BATCH 4
#define SEQ 1024
#define TOK (BATCH * SEQ)          // 4096
#define NQKV 12288                 // (HQ + 2*HKV) * DH
#define CACHE_ROWS 8192            // NUM_BLOCKS * BLOCK_SIZE
#define SM_SCALE 0.08838834764831845f  // 1/sqrt(128)

typedef unsigned short u16;
typedef __bf16 bf16x8 __attribute__((ext_vector_type(8)));
typedef float floatx4 __attribute__((ext_vector_type(4)));
typedef u16 u16x8 __attribute__((ext_vector_type(8)));
typedef u16 u16x4 __attribute__((ext_vector_type(4)));

__device__ __forceinline__ u16 f2bf(float x) {
  unsigned u = __float_as_uint(x);
  u += 0x7FFF + ((u >> 16) & 1);   // RNE
  return (u16)(u >> 16);
}
__device__ __forceinline__ float bf2f(u16 h) {
  return __uint_as_float(((unsigned)h) << 16);
}
// async global->LDS, 16B per lane. LDS dest is wave-uniform base + lane*16:
// callers must pass per-lane pointers that are lane-contiguous within a wave.
__device__ __forceinline__ void cp16(const void* g, void* l) {
  __builtin_amdgcn_global_load_lds(
      (__attribute__((address_space(1))) unsigned int*)(g),
      (__attribute__((address_space(3))) unsigned int*)(l), 16, 0, 0);
}

// ---------------- fp32 -> bf16 elementwise ----------------
__global__ void k_f32_to_bf16(const float4* __restrict__ x, ushort4* __restrict__ y) {
  int i = blockIdx.x * 256 + threadIdx.x;
  float4 v = x[i];
  ushort4 o;
  o.x = f2bf(v.x); o.y = f2bf(v.y); o.z = f2bf(v.z); o.w = f2bf(v.w);
  y[i] = o;
}

// ---------------- fp32 KxN -> bf16 NxK transpose ----------------
// read coalesced fp32; write ushort4 (4 k per lane) for 512B/wave-instr stores
__global__ void k_transpose_bf16(const float* __restrict__ W, u16* __restrict__ Wt,
                                 int Kd, int Nd) {
  __shared__ float t[64][65];
  int n0 = blockIdx.x << 6, k0 = blockIdx.y << 6;
  int tx = threadIdx.x & 63, ty = threadIdx.x >> 6;
#pragma unroll
  for (int r = ty; r < 64; r += 4)
    t[r][tx] = W[(size_t)(k0 + r) * Nd + n0 + tx];
  __syncthreads();
  const int kg = threadIdx.x & 15, nr = threadIdx.x >> 4;  // kg: k-group, nr: 0..15
#pragma unroll
  for (int q = 0; q < 4; ++q) {
    int n = q * 16 + nr;
    u16x4 o;
#pragma unroll
    for (int j = 0; j < 4; ++j) o[j] = f2bf(t[kg * 4 + j][n]);
    *(u16x4*)&Wt[(size_t)(n0 + n) * Kd + k0 + kg * 4] = o;
  }
}

// ================= 256x256 8-phase bf16 GEMM =================
// Block remap: XCD-chunked linear j, then 4-row bands with by-minor order so
// each XCD's 32 concurrent blocks form a 4(by)x8(bx) supertile:
// per-round unique panels = A 32MB + B 32MB (L3-resident) -> B fetched ~once.
template <int Nd, int Kd, bool OUT_BF16>
__global__ __launch_bounds__(512, 2) void k_gemm256(const u16* __restrict__ A,
                                                    const u16* __restrict__ Bt,
                                                    void* __restrict__ Cp) {
  constexpr int GX = Nd / 256;
  constexpr int NWG = (TOK / 256) * GX;
  constexpr int BAND = 4 * GX;
  __shared__ __align__(16) u16 lds[2][2][256 * 64];  // [buf][0=A,1=B]

  const int bid = blockIdx.x;
  const int j = (bid & 7) * (NWG / 8) + (bid >> 3);  // XCD-chunked linear
  const int band = j / BAND, r = j % BAND;
  const int by = band * 4 + (r & 3), bx = r >> 2;
  const int bm = by << 8, bn = bx << 8;

  const int tid = threadIdx.x;
  const int wave = tid >> 6, lane = tid & 63;
  const int wm = wave >> 2, wn = wave & 3;
  const int quad = lane >> 4, l16 = lane & 15;

  auto stage_half = [&](const u16* src, int grow, int k0, u16* ldsb, int h) {
#pragma unroll
    for (int p = 0; p < 2; ++p) {
      int g = tid + (p << 9);
      int row = g >> 3, ps = g & 7;
      int ls = ps ^ (row & 7);
      cp16(src + (size_t)(grow + h * 128 + row) * Kd + k0 + ls * 8,
           ldsb + ((h * 128 + row) << 6) + (ps << 3));
    }
  };
  auto frag = [&](const u16* ldsb, int row, int slot) {
    return (const bf16x8*)(ldsb + (row << 6) + ((slot ^ (row & 7)) << 3));
  };

  const floatx4 FZ4 = {0.f, 0.f, 0.f, 0.f};
  floatx4 acc[8][4];
#pragma unroll
  for (int i = 0; i < 8; ++i)
#pragma unroll
    for (int j2 = 0; j2 < 4; ++j2) acc[i][j2] = FZ4;

  stage_half(A, bm, 0, &lds[0][0][0], 0);
  stage_half(A, bm, 0, &lds[0][0][0], 1);
  stage_half(Bt, bn, 0, &lds[0][1][0], 0);
  stage_half(Bt, bn, 0, &lds[0][1][0], 1);
  stage_half(Bt, bn, 64, &lds[1][1][0], 0);
  stage_half(Bt, bn, 64, &lds[1][1][0], 1);
  asm volatile("s_waitcnt vmcnt(4)" ::: "memory");
  asm volatile("s_barrier" ::: "memory");

  constexpr int NT = Kd / 64;
  for (int t = 0; t < NT; ++t) {
    const int c = t & 1, o = c ^ 1;
    const u16* cA = &lds[c][0][0];
    const u16* cB = &lds[c][1][0];
    const int k1 = (t + 1 < NT) ? (t + 1) * 64 : (Kd - 64);
    const int k2 = (t + 2 < NT) ? (t + 2) * 64 : (Kd - 64);

    bf16x8 bfr[4][2];
#pragma unroll
    for (int ph = 0; ph < 4; ++ph) {
      if (ph == 0) {
#pragma unroll
        for (int ni = 0; ni < 4; ++ni)
#pragma unroll
          for (int ks = 0; ks < 2; ++ks)
            bfr[ni][ks] = *frag(cB, wn * 64 + ni * 16 + l16, ks * 4 + quad);
      }
      bf16x8 af[2][2];
#pragma unroll
      for (int m = 0; m < 2; ++m)
#pragma unroll
        for (int ks = 0; ks < 2; ++ks)
          af[m][ks] = *frag(cA, wm * 128 + (ph * 2 + m) * 16 + l16, ks * 4 + quad);

      if (ph == 0) stage_half(A, bm, k1, &lds[o][0][0], 0);
      else if (ph == 1) stage_half(A, bm, k1, &lds[o][0][0], 1);
      else if (ph == 2) stage_half(Bt, bn, k2, &lds[c][1][0], 0);
      else stage_half(Bt, bn, k2, &lds[c][1][0], 1);

      asm volatile("s_barrier" ::: "memory");
      __builtin_amdgcn_s_setprio(1);
#pragma unroll
      for (int m = 0; m < 2; ++m)
#pragma unroll
        for (int ni = 0; ni < 4; ++ni)
#pragma unroll
          for (int ks = 0; ks < 2; ++ks)
            acc[ph * 2 + m][ni] = __builtin_amdgcn_mfma_f32_16x16x32_bf16(
                af[m][ks], bfr[ni][ks], acc[ph * 2 + m][ni], 0, 0, 0);
      __builtin_amdgcn_s_setprio(0);
      if (ph == 3) asm volatile("s_waitcnt vmcnt(4)" ::: "memory");
      asm volatile("s_barrier" ::: "memory");
    }
  }
  asm volatile("s_waitcnt vmcnt(0)" ::: "memory");

  const int rbase = bm + wm * 128 + quad * 4;
  const int cbase = bn + wn * 64 + l16;
#pragma unroll
  for (int mi = 0; mi < 8; ++mi)
#pragma unroll
    for (int ni = 0; ni < 4; ++ni)
#pragma unroll
      for (int r2 = 0; r2 < 4; ++r2) {
        size_t idx = (size_t)(rbase + mi * 16 + r2) * Nd + (cbase + ni * 16);
        if (OUT_BF16)
          ((u16*)Cp)[idx] = f2bf(acc[mi][ni][r2]);
        else
          ((float*)Cp)[idx] = acc[mi][ni][r2];
      }
}

// ---------------- RoPE + layout + cache scatter (vectorized) ----------------
__global__ void k_rope_scatter(const u16* __restrict__ qkv, const float* __restrict__ cosp,
                               const float* __restrict__ sinp, const int* __restrict__ slots,
                               u16* __restrict__ qb, u16* __restrict__ kb,
                               float* __restrict__ kc, float* __restrict__ vc) {
  const int t = blockIdx.x;
  const int b = t >> 10, s = t & 1023;
  const int tid = threadIdx.x;
  __shared__ float lc[64], ls[64];
  if (tid < 64) lc[tid] = cosp[t * 64 + tid];
  else if (tid < 128) ls[tid - 64] = sinp[t * 64 + (tid - 64)];
  __syncthreads();
  const int slot = slots[t];
  const u16* base = qkv + (size_t)t * NQKV;
  const int h = tid >> 3, i0 = (tid & 7) << 3;
  float c[8], sn[8];
#pragma unroll
  for (int j = 0; j < 8; ++j) { c[j] = lc[i0 + j]; sn[j] = ls[i0 + j]; }

  {  // Q (scale folded)
    u16x8 x1 = *(const u16x8*)&base[h * 128 + i0];
    u16x8 x2 = *(const u16x8*)&base[h * 128 + 64 + i0];
    u16x8 y1, y2;
#pragma unroll
    for (int j = 0; j < 8; ++j) {
      float a = bf2f(x1[j]), d = bf2f(x2[j]);
      y1[j] = f2bf((a * c[j] - d * sn[j]) * SM_SCALE);
      y2[j] = f2bf((d * c[j] + a * sn[j]) * SM_SCALE);
    }
    size_t o = ((size_t)(b * HQ + h) * SEQ + s) * DH + i0;
    *(u16x8*)&qb[o] = y1;
    *(u16x8*)&qb[o + 64] = y2;
  }
  {  // K: bf16 kb + fp32 cache
    u16x8 x1 = *(const u16x8*)&base[HQ * DH + h * 128 + i0];
    u16x8 x2 = *(const u16x8*)&base[HQ * DH + h * 128 + 64 + i0];
    u16x8 y1, y2;
    float f1[8], f2[8];
#pragma unroll
    for (int j = 0; j < 8; ++j) {
      float a = bf2f(x1[j]), d = bf2f(x2[j]);
      f1[j] = a * c[j] - d * sn[j];
      f2[j] = d * c[j] + a * sn[j];
      y1[j] = f2bf(f1[j]);
      y2[j] = f2bf(f2[j]);
    }
    size_t o = ((size_t)(b * HKV + h) * SEQ + s) * DH + i0;
    *(u16x8*)&kb[o] = y1;
    *(u16x8*)&kb[o + 64] = y2;
    size_t oc = (size_t)slot * (HKV * DH) + h * 128 + i0;
    *(float4*)&kc[oc]      = make_float4(f1[0], f1[1], f1[2], f1[3]);
    *(float4*)&kc[oc + 4]  = make_float4(f1[4], f1[5], f1[6], f1[7]);
    *(float4*)&kc[oc + 64] = make_float4(f2[0], f2[1], f2[2], f2[3]);
    *(float4*)&kc[oc + 68] = make_float4(f2[4], f2[5], f2[6], f2[7]);
  }
  {  // V -> fp32 cache; thread owns 16 consecutive channels
    const int vo = tid * 16;
    u16x8 va = *(const u16x8*)&base[2 * HQ * DH + vo];
    u16x8 vb2 = *(const u16x8*)&base[2 * HQ * DH + vo + 8];
    float* vd = vc + (size_t)slot * (HKV * DH) + vo;
    *(float4*)&vd[0]  = make_float4(bf2f(va[0]), bf2f(va[1]), bf2f(va[2]), bf2f(va[3]));
    *(float4*)&vd[4]  = make_float4(bf2f(va[4]), bf2f(va[5]), bf2f(va[6]), bf2f(va[7]));
    *(float4*)&vd[8]  = make_float4(bf2f(vb2[0]), bf2f(vb2[1]), bf2f(vb2[2]), bf2f(vb2[3]));
    *(float4*)&vd[12] = make_float4(bf2f(vb2[4]), bf2f(vb2[5]), bf2f(vb2[6]), bf2f(vb2[7]));
  }
}

// ---------------- V transpose: qkv v-slice -> vT (b,h,d,s) bf16 ----------------
__global__ void k_vt(const u16* __restrict__ qkv, u16* __restrict__ vT) {
  __shared__ u16 t[64][66];
  const int bh = blockIdx.z;
  const int b = bh >> 5, h = bh & 31;
  const int s0 = blockIdx.y << 6, d0 = blockIdx.x << 6;
  const int cg = threadIdx.x & 15, rr = threadIdx.x >> 4;  // 16 col-groups x 16 rows
#pragma unroll
  for (int q = 0; q < 4; ++q) {
    int r = q * 16 + rr;
    u16x4 v = *(const u16x4*)&qkv[(size_t)(b * SEQ + s0 + r) * NQKV + 2 * HQ * DH +
                                  h * DH + d0 + cg * 4];
    *(u16x4*)&t[r][cg * 4] = v;
  }
  __syncthreads();
#pragma unroll
  for (int q = 0; q < 4; ++q) {
    int d = q * 16 + rr;
    u16x4 o;
#pragma unroll
    for (int j = 0; j < 4; ++j) o[j] = t[cg * 4 + j][d];
    *(u16x4*)&vT[((size_t)bh * DH + d0 + d) * SEQ + s0 + cg * 4] = o;
  }
}

// ---------------- flash attention (causal), QBLK=128 ----------------
// 8 waves x 16 q-rows; K/V dbuf in LDS, counted vmcnt(4); XOR-swizzled LDS.
// LDS = 2*16K (K) + 2*16K (V) + 16K (P) = 80KB -> 2 blocks/CU (160KB exact).
__global__ __launch_bounds__(512, 4) void k_attn(const u16* __restrict__ qb,
                                                 const u16* __restrict__ kb,
                                                 const u16* __restrict__ vT,
                                                 u16* __restrict__ attn) {
  __shared__ __align__(16) u16 lK[2][64 * 128];
  __shared__ __align__(16) u16 lV[2][128 * 64];
  __shared__ __align__(16) u16 lP[128 * 64];
  const int qt = blockIdx.x, h = blockIdx.y, b = blockIdx.z;
  const int bh = b * HQ + h;
  const int q0 = qt << 7;
  const int tid = threadIdx.x, wave = tid >> 6, lane = tid & 63;
  const int quad = lane >> 4, l16 = lane & 15;
  const u16* Qb = qb + (size_t)bh * SEQ * DH;
  const u16* Kb = kb + (size_t)bh * SEQ * DH;
  const u16* Vb = vT + (size_t)bh * DH * SEQ;

  bf16x8 qf[4];
#pragma unroll
  for (int ds = 0; ds < 4; ++ds)
    qf[ds] = *(const bf16x8*)&Qb[(size_t)(q0 + wave * 16 + l16) * DH + ds * 32 + quad * 8];

  const floatx4 FZ4 = {0.f, 0.f, 0.f, 0.f};
  floatx4 acc_o[8];
#pragma unroll
  for (int i = 0; i < 8; ++i) acc_o[i] = FZ4;
  float m_i[4] = {-1e30f, -1e30f, -1e30f, -1e30f};
  float l_i[4] = {0.f, 0.f, 0.f, 0.f};

  auto stageK = [&](int buf, int k0) {
#pragma unroll
    for (int p = 0; p < 2; ++p) {
      int g = tid + (p << 9);               // granule 0..1023 of [64][128]
      int row = g >> 4, gs = g & 15;
      int sl = gs ^ (row & 15);             // pre-swizzled source column
      cp16(Kb + (size_t)(k0 + row) * DH + sl * 8, &lK[buf][g * 8]);
    }
  };
  auto stageV = [&](int buf, int k0) {
#pragma unroll
    for (int p = 0; p < 2; ++p) {
      int g = tid + (p << 9);               // granule 0..1023 of [128][64]
      int row = g >> 3, gs = g & 7;         // row = d
      int sl = gs ^ (row & 7);
      cp16(Vb + (size_t)row * SEQ + k0 + sl * 8, &lV[buf][g * 8]);
    }
  };

  const int ktmax = 2 * qt + 1;             // cover q rows up to q0+127
  stageK(0, 0);
  stageV(0, 0);
  for (int kt = 0; kt <= ktmax; ++kt) {
    const int cur = kt & 1;
    const int k0 = kt << 6;
    if (kt < ktmax) {
      stageK(cur ^ 1, k0 + 64);
      stageV(cur ^ 1, k0 + 64);
      asm volatile("s_waitcnt vmcnt(4)" ::: "memory");  // cur's 4 done; 4 in flight
    } else {
      asm volatile("s_waitcnt vmcnt(0)" ::: "memory");
    }
    __builtin_amdgcn_s_barrier();  // tile cur visible to all waves

    // S = Q K^T (scale folded in Q); swizzled kf reads are conflict-free
    floatx4 accs[4];
    __builtin_amdgcn_s_setprio(1);
#pragma unroll
    for (int ni = 0; ni < 4; ++ni) {
      accs[ni] = FZ4;
      const int row = ni * 16 + l16;
#pragma unroll
      for (int ds = 0; ds < 4; ++ds) {
        bf16x8 kf = *(const bf16x8*)&lK[cur][row * 128 + (((ds * 4 + quad) ^ (row & 15)) << 3)];
        accs[ni] = __builtin_amdgcn_mfma_f32_16x16x32_bf16(qf[ds], kf, accs[ni], 0, 0, 0);
      }
    }
    __builtin_amdgcn_s_setprio(0);
    // causal mask: needed iff tile's max ki can exceed wave's min q-row
    if (k0 + 63 > q0 + wave * 16) {
#pragma unroll
      for (int ni = 0; ni < 4; ++ni) {
        int ki = k0 + ni * 16 + l16;
#pragma unroll
        for (int r = 0; r < 4; ++r) {
          int qr = q0 + wave * 16 + quad * 4 + r;
          if (ki > qr) accs[ni][r] = -1e30f;
        }
      }
    }
    // online softmax; rows live on 16 lanes of a quad
    float mnew[4], alpha[4];
#pragma unroll
    for (int r = 0; r < 4; ++r) {
      float mx = fmaxf(fmaxf(accs[0][r], accs[1][r]), fmaxf(accs[2][r], accs[3][r]));
#pragma unroll
      for (int off = 1; off < 16; off <<= 1) mx = fmaxf(mx, __shfl_xor(mx, off));
      mnew[r] = fmaxf(m_i[r], mx);
      alpha[r] = __expf(m_i[r] - mnew[r]);
      m_i[r] = mnew[r];
    }
    float rs[4] = {0.f, 0.f, 0.f, 0.f};
#pragma unroll
    for (int ni = 0; ni < 4; ++ni)
#pragma unroll
      for (int r = 0; r < 4; ++r) {
        float p = __expf(accs[ni][r] - mnew[r]);
        rs[r] += p;
        int prow = wave * 16 + quad * 4 + r, pcol = ni * 16 + l16;
        lP[prow * 64 + ((((pcol >> 3) ^ (prow & 7))) << 3) + (pcol & 7)] = f2bf(p);
      }
#pragma unroll
    for (int r = 0; r < 4; ++r) {
      float sr = rs[r];
#pragma unroll
      for (int off = 1; off < 16; off <<= 1) sr += __shfl_xor(sr, off);
      l_i[r] = l_i[r] * alpha[r] + sr;
    }
#pragma unroll
    for (int dt = 0; dt < 8; ++dt)
#pragma unroll
      for (int r = 0; r < 4; ++r) acc_o[dt][r] *= alpha[r];

    // O += P V (wave-local P rows; swizzled pf/vf reads)
    bf16x8 pf[2];
    const int prow = wave * 16 + l16;
#pragma unroll
    for (int ks = 0; ks < 2; ++ks)
      pf[ks] = *(const bf16x8*)&lP[prow * 64 + (((ks * 4 + quad) ^ (prow & 7)) << 3)];
    __builtin_amdgcn_s_setprio(1);
#pragma unroll
    for (int dt = 0; dt < 8; ++dt) {
      const int vrow = dt * 16 + l16;
#pragma unroll
      for (int ks = 0; ks < 2; ++ks) {
        bf16x8 vf = *(const bf16x8*)&lV[cur][vrow * 64 + (((ks * 4 + quad) ^ (vrow & 7)) << 3)];
        acc_o[dt] = __builtin_amdgcn_mfma_f32_16x16x32_bf16(pf[ks], vf, acc_o[dt], 0, 0, 0);
      }
    }
    __builtin_amdgcn_s_setprio(0);
    // all LDS reads of tile cur retired before next iter restages cur^1's buddy
    asm volatile("s_waitcnt lgkmcnt(0)" ::: "memory");
    __builtin_amdgcn_s_barrier();
  }
  float inv[4];
#pragma unroll
  for (int r = 0; r < 4; ++r) inv[r] = 1.0f / l_i[r];
#pragma unroll
  for (int dt = 0; dt < 8; ++dt)
#pragma unroll
    for (int r = 0; r < 4; ++r) {
      int tok = b * SEQ + q0 + wave * 16 + quad * 4 + r;
      attn[(size_t)tok * HID + h * DH + dt * 16 + l16] = f2bf(acc_o[dt][r] * inv[r]);
    }
}

// ---------------- launcher ----------------
extern "C" void kernel_launch(void* const* d_in, const int* in_sizes, int n_in,
                              void* d_out, int out_size, void* d_ws, size_t ws_size,
                              hipStream_t stream) {
  (void)in_sizes; (void)n_in; (void)out_size; (void)ws_size;
  const float* hs = (const float*)d_in[0];
  const float* cosp = (const float*)d_in[1];
  const float* sinp = (const float*)d_in[2];
  const float* qkv_w = (const float*)d_in[3];
  const float* o_w = (const float*)d_in[4];
  const int* slots = (const int*)d_in[8];

  float* out = (float*)d_out;                          // (T, HID) fp32
  float* kc = out + (size_t)TOK * HID;                 // (8192, 32, 128) fp32
  float* vc = kc + (size_t)CACHE_ROWS * HKV * DH;

  // workspace layout (224 MiB), stream-ordered aliasing:
  //  regA (96MB): W1t  -> then qb | kb | vT
  //  regB (96MB): qkv  -> then W2t (after v-transpose consumed qkv)
  //  regC (32MB): hs_bf16 -> then attn
  u16* regA = (u16*)d_ws;
  u16* regB = regA + (size_t)NQKV * HID;
  u16* regC = regB + (size_t)TOK * NQKV;
  u16* W1t = regA;
  u16* qb = regA;
  u16* kb = qb + (size_t)BATCH * HQ * SEQ * DH;
  u16* vTp = kb + (size_t)BATCH * HKV * SEQ * DH;
  u16* qkv = regB;
  u16* W2t = regB;
  u16* hsb = regC;
  u16* attnb = regC;

  // slots = arange(TOK) fully overwrites cache rows [0, TOK); zero only the rest
  const size_t halfRows = (size_t)(CACHE_ROWS - TOK) * HKV * DH;
  hipMemsetAsync(kc + (size_t)TOK * HKV * DH, 0, halfRows * sizeof(float), stream);
  hipMemsetAsync(vc + (size_t)TOK * HKV * DH, 0, halfRows * sizeof(float), stream);

  k_f32_to_bf16<<<TOK * HID / 1024, 256, 0, stream>>>((const float4*)hs, (ushort4*)hsb);
  k_transpose_bf16<<<dim3(NQKV / 64, HID / 64), 256, 0, stream>>>(qkv_w, W1t, HID, NQKV);
  k_gemm256<NQKV, HID, true>
      <<<(TOK / 256) * (NQKV / 256), 512, 0, stream>>>(hsb, W1t, qkv);
  k_rope_scatter<<<TOK, 256, 0, stream>>>(qkv, cosp, sinp, slots, qb, kb, kc, vc);
  k_vt<<<dim3(DH / 64, SEQ / 64, BATCH * HKV), 256, 0, stream>>>(qkv, vTp);
  k_transpose_bf16<<<dim3(HID / 64, HID / 64), 256, 0, stream>>>(o_w, W2t, HID, HID);
  k_attn<<<dim3(SEQ / 128, HQ, BATCH), 512, 0, stream>>>(qb, kb, vTp, attnb);
  k_gemm256<HID, HID, false>
      <<<(TOK / 256) * (HID / 256), 512, 0, stream>>>(attnb, W2t, out);
}